// Round 2
// baseline (67659.033 us; speedup 1.0000x reference)
//
#include <hip/hip_runtime.h>
#include <hip/hip_cooperative_groups.h>
#include <stdint.h>

namespace cg = cooperative_groups;

// ---------------- problem constants ----------------
#define TN     2048     // time steps
#define NBLK   192      // 64 A-blocks (cell1) + 128 B-blocks (cell2), pipelined
#define NA     64

// LDS layout (padded strides -> no bank conflicts, no swizzle):
//  A-blocks: wlds bf16 [96 rows][stride 520]            (99840 B used)
//  B-blocks: region0 [32][1032] + region1/2 [16][520]   (99328 B used)
//  exch  f32 [128][16] at byte 99840  (8192 B)
//  fmisc f32 [320]     at byte 108032
#define R1BASE 33024            // 32*1032
#define R2BASE 41344            // R1BASE + 16*520
#define EXCH_OFF  99840
#define FMISC_OFF 108032
#define SMEM_BYTES 109312

// ws layout: h0x bf16[2][256][512] at 0; h1x bf16[2][256][512] at 524288.
// Total 1 MiB. Parity p holds state(t) with t&1==p; parity 1 inited to state(-1).

typedef __attribute__((ext_vector_type(8))) short bf16x8;
typedef __attribute__((ext_vector_type(4))) float f32x4;

__device__ __forceinline__ float sigf(float v)   { return 1.0f / (1.0f + __expf(-v)); }
__device__ __forceinline__ float tanhf_(float v) { return 2.0f / (1.0f + __expf(-2.0f * v)) - 1.0f; }
__device__ __forceinline__ unsigned short f2bf(float f) {
  unsigned u = __float_as_uint(f);
  u += 0x7fffu + ((u >> 16) & 1u);   // RNE
  return (unsigned short)(u >> 16);
}

extern "C" __global__ void __launch_bounds__(256, 1)
gru_main(const float* __restrict__ x,
         const float* __restrict__ W_ih1, const float* __restrict__ W_hh1,
         const float* __restrict__ b_ih1, const float* __restrict__ b_hh1,
         const float* __restrict__ W_ih2, const float* __restrict__ W_hh2,
         const float* __restrict__ b_ih2, const float* __restrict__ b_hh2,
         const float* __restrict__ W_out, const float* __restrict__ b_out,
         const float* __restrict__ h0in, const float* __restrict__ h1in,
         float* __restrict__ out, char* __restrict__ ws)
{
  extern __shared__ char smem[];
  unsigned short* wlds = (unsigned short*)smem;
  float* exch  = (float*)(smem + EXCH_OFF);
  float* fmisc = (float*)(smem + FMISC_OFF);

  unsigned short* h0x = (unsigned short*)ws;
  unsigned short* h1x = (unsigned short*)(ws + 524288);

  const int bid = blockIdx.x, tid = threadIdx.x;
  const int w = tid >> 6, l = tid & 63, l15 = l & 15, l4 = l >> 4;
  const bool isA = (bid < NA);
  const int p_ = w >> 1;     // M half: rows 0-31 / 32-63 of the 64-row batch tile
  const int hh = w & 1;      // A: column half (2x16 of 32); B: gate role (r,in_ / z,hn)

  int bt, S;
  if (isA) { bt = bid >> 4; S = (bid & 15) * 32; }                 // 4 bt x 16 groups of 32 cols
  else     { int bb = bid - NA; bt = bb >> 5; S = (bb & 31) * 16; }// 4 bt x 32 groups of 16 cols

  // ---------------- init: bf16 state mirrors (parity 1), out = b_out ----------------
  {
    int gid = bid * 256 + tid;
    for (int i = gid; i < 131072; i += NBLK * 256) {
      h0x[131072 + i] = f2bf(h0in[i]);
      h1x[131072 + i] = f2bf(h1in[i]);
    }
    if (bid == 0) out[tid] = b_out[0];
  }

  // ---------------- weight preload into LDS (bf16, padded strides) ----------------
  if (isA) {
    for (int idx = tid; idx < 96 * 512; idx += 256) {
      int j = idx >> 9, kk = idx & 511;
      int h = j / 48, rr = j % 48, g = rr >> 4, c2 = rr & 15;
      int grow = g * 512 + S + h * 16 + c2;
      wlds[j * 520 + kk] = f2bf(W_hh1[grow * 512 + kk]);
    }
    if (tid < 96) {
      int j = tid, h = j / 48, rr = j % 48, g = rr >> 4, c2 = rr & 15;
      int grow = g * 512 + S + h * 16 + c2;
      fmisc[j]       = W_ih1[grow];
      fmisc[96 + j]  = b_ih1[grow];
      fmisc[192 + j] = b_hh1[grow];
    }
  } else {
    // region0: rows 0..15 = r-gate, 16..31 = z-gate; K=1024 = [W_ih2 | W_hh2]
    for (int idx = tid; idx < 32 * 1024; idx += 256) {
      int j = idx >> 10, kk = idx & 1023;
      int g = j >> 4, c2 = S + (j & 15);
      float v = (kk < 512) ? W_ih2[(g * 512 + c2) * 512 + kk]
                           : W_hh2[(g * 512 + c2) * 512 + kk - 512];
      wlds[j * 1032 + kk] = f2bf(v);
    }
    // region1: in_ rows (W_ih2 n-gate); region2: hn rows (W_hh2 n-gate); K=512
    for (int idx = tid; idx < 16 * 512; idx += 256) {
      int j2 = idx >> 9, kk = idx & 511;
      wlds[R1BASE + j2 * 520 + kk] = f2bf(W_ih2[(1024 + S + j2) * 512 + kk]);
      wlds[R2BASE + j2 * 520 + kk] = f2bf(W_hh2[(1024 + S + j2) * 512 + kk]);
    }
    if (tid < 48) {
      int g = tid >> 4, c2 = S + (tid & 15);
      fmisc[tid]      = b_ih2[g * 512 + c2];
      fmisc[48 + tid] = b_hh2[g * 512 + c2];
    }
  }
  __syncthreads();

  cg::grid_group grid = cg::this_grid();
  grid.sync();   // init + weights visible everywhere

  // ---------------- per-thread constants / carries ----------------
  int rowb[2][4];
  int arowOff[2];
  #pragma unroll
  for (int mtl = 0; mtl < 2; ++mtl) {
    arowOff[mtl] = ((p_ * 2 + mtl) * 16 + l15) * 512;     // A-fragment row (lane&15-based)
    #pragma unroll
    for (int q = 0; q < 4; ++q)
      rowb[mtl][q] = bt * 64 + (p_ * 2 + mtl) * 16 + l4 * 4 + q;  // D row (reg-based)
  }

  float carry[2][4];
  #pragma unroll
  for (int mtl = 0; mtl < 2; ++mtl)
    #pragma unroll
    for (int q = 0; q < 4; ++q) carry[mtl][q] = 0.0f;
  if (isA) {
    int c = S + hh * 16 + l15;
    #pragma unroll
    for (int mtl = 0; mtl < 2; ++mtl)
      #pragma unroll
      for (int q = 0; q < 4; ++q) carry[mtl][q] = h0in[rowb[mtl][q] * 512 + c];
  } else if (hh == 1) {
    int c = S + l15;
    #pragma unroll
    for (int mtl = 0; mtl < 2; ++mtl)
      #pragma unroll
      for (int q = 0; q < 4; ++q) carry[mtl][q] = h1in[rowb[mtl][q] * 512 + c];
  }
  const float wout = (!isA && hh == 1) ? W_out[S + l15] : 0.0f;

  // ---------------- tick loop (A computes h0(k); B computes h1(k-1)) ----------------
  for (int k = 0; k <= TN; ++k) {
    if (isA && k < TN) {
      float xv[2][4];
      #pragma unroll
      for (int mtl = 0; mtl < 2; ++mtl)
        #pragma unroll
        for (int q = 0; q < 4; ++q) xv[mtl][q] = x[rowb[mtl][q] * 2048 + k];

      f32x4 acc[2][3];
      #pragma unroll
      for (int mtl = 0; mtl < 2; ++mtl)
        #pragma unroll
        for (int g = 0; g < 3; ++g) acc[mtl][g] = f32x4{0.f, 0.f, 0.f, 0.f};

      const unsigned short* srcA = h0x + ((k + 1) & 1) * 131072 + bt * 32768; // h0(k-1)
      #pragma unroll 4
      for (int ks = 0; ks < 16; ++ks) {
        bf16x8 af[2];
        #pragma unroll
        for (int mtl = 0; mtl < 2; ++mtl)
          af[mtl] = *(const bf16x8*)(srcA + arowOff[mtl] + ks * 32 + l4 * 8);
        #pragma unroll
        for (int g = 0; g < 3; ++g) {
          bf16x8 bw = *(const bf16x8*)(wlds + (hh * 48 + g * 16 + l15) * 520 + ks * 32 + l4 * 8);
          #pragma unroll
          for (int mtl = 0; mtl < 2; ++mtl)
            acc[mtl][g] = __builtin_amdgcn_mfma_f32_16x16x32_bf16(af[mtl], bw, acc[mtl][g], 0, 0, 0);
        }
      }

      int cc = S + hh * 16 + l15;
      int jb = hh * 48 + l15;
      float wir = fmisc[jb],       wiz = fmisc[jb + 16],       win = fmisc[jb + 32];
      float bir = fmisc[96 + jb],  biz = fmisc[96 + jb + 16],  bin = fmisc[96 + jb + 32];
      float bhr = fmisc[192 + jb], bhz = fmisc[192 + jb + 16], bhn = fmisc[192 + jb + 32];
      unsigned short* dsth = h0x + (k & 1) * 131072;
      #pragma unroll
      for (int mtl = 0; mtl < 2; ++mtl)
        #pragma unroll
        for (int q = 0; q < 4; ++q) {
          float rg = sigf(xv[mtl][q] * wir + bir + acc[mtl][0][q] + bhr);
          float zg = sigf(xv[mtl][q] * wiz + biz + acc[mtl][1][q] + bhz);
          float ng = tanhf_(xv[mtl][q] * win + bin + rg * (acc[mtl][2][q] + bhn));
          float hv = (1.0f - zg) * ng + zg * carry[mtl][q];
          carry[mtl][q] = hv;
          dsth[rowb[mtl][q] * 512 + cc] = f2bf(hv);
        }
    } else if (!isA && k >= 1) {
      f32x4 acc[2][2];
      #pragma unroll
      for (int mtl = 0; mtl < 2; ++mtl)
        #pragma unroll
        for (int g = 0; g < 2; ++g) acc[mtl][g] = f32x4{0.f, 0.f, 0.f, 0.f};

      const unsigned short* src0 = h0x + ((k + 1) & 1) * 131072 + bt * 32768; // h0(k-1)
      const unsigned short* src1 = h1x + (k & 1) * 131072 + bt * 32768;       // h1(k-2)

      #pragma unroll 4
      for (int ks = 0; ks < 32; ++ks) {
        const unsigned short* s = (ks < 16) ? src0 : src1;
        int koff = (ks & 15) * 32;
        bf16x8 af[2];
        #pragma unroll
        for (int mtl = 0; mtl < 2; ++mtl)
          af[mtl] = *(const bf16x8*)(s + arowOff[mtl] + koff + l4 * 8);
        bf16x8 b0 = *(const bf16x8*)(wlds + (hh * 16 + l15) * 1032 + ks * 32 + l4 * 8);
        #pragma unroll
        for (int mtl = 0; mtl < 2; ++mtl)
          acc[mtl][0] = __builtin_amdgcn_mfma_f32_16x16x32_bf16(af[mtl], b0, acc[mtl][0], 0, 0, 0);
        if (hh == 0) {
          if (ks < 16) {
            bf16x8 b1 = *(const bf16x8*)(wlds + R1BASE + l15 * 520 + ks * 32 + l4 * 8);
            #pragma unroll
            for (int mtl = 0; mtl < 2; ++mtl)
              acc[mtl][1] = __builtin_amdgcn_mfma_f32_16x16x32_bf16(af[mtl], b1, acc[mtl][1], 0, 0, 0);
          }
        } else {
          if (ks >= 16) {
            bf16x8 b1 = *(const bf16x8*)(wlds + R2BASE + l15 * 520 + (ks - 16) * 32 + l4 * 8);
            #pragma unroll
            for (int mtl = 0; mtl < 2; ++mtl)
              acc[mtl][1] = __builtin_amdgcn_mfma_f32_16x16x32_bf16(af[mtl], b1, acc[mtl][1], 0, 0, 0);
          }
        }
      }

      // exchange r/in_ (hh0) -> hh1 waves
      if (hh == 0) {
        #pragma unroll
        for (int mtl = 0; mtl < 2; ++mtl)
          #pragma unroll
          for (int qn = 0; qn < 2; ++qn)
            #pragma unroll
            for (int q = 0; q < 4; ++q)
              exch[((p_ * 2 + qn) * 32 + mtl * 16 + l4 * 4 + q) * 16 + l15] = acc[mtl][qn][q];
      }
      __syncthreads();
      if (hh == 1) {
        int cc = S + l15;
        float bir = fmisc[l15],      biz = fmisc[16 + l15], bin = fmisc[32 + l15];
        float bhr = fmisc[48 + l15], bhz = fmisc[64 + l15], bhn = fmisc[80 + l15];
        unsigned short* dsth = h1x + ((k + 1) & 1) * 131072;
        #pragma unroll
        for (int mtl = 0; mtl < 2; ++mtl)
          #pragma unroll
          for (int q = 0; q < 4; ++q) {
            float rv = exch[((p_ * 2 + 0) * 32 + mtl * 16 + l4 * 4 + q) * 16 + l15];
            float iv = exch[((p_ * 2 + 1) * 32 + mtl * 16 + l4 * 4 + q) * 16 + l15];
            float rg = sigf(rv + bir + bhr);
            float zg = sigf(acc[mtl][0][q] + biz + bhz);
            float ng = tanhf_(iv + bin + rg * (acc[mtl][1][q] + bhn));
            float hv = (1.0f - zg) * ng + zg * carry[mtl][q];
            carry[mtl][q] = hv;
            dsth[rowb[mtl][q] * 512 + cc] = f2bf(hv);
            if (k == TN) atomicAdd(&out[rowb[mtl][q]], hv * wout);  // final projection partials
          }
      }
    }

    grid.sync();
  }
}

extern "C" void kernel_launch(void* const* d_in, const int* in_sizes, int n_in,
                              void* d_out, int out_size, void* d_ws, size_t ws_size,
                              hipStream_t stream) {
  const float* x     = (const float*)d_in[0];
  const float* h0in  = (const float*)d_in[1];
  const float* h1in  = (const float*)d_in[2];
  const float* W_ih1 = (const float*)d_in[3];
  const float* W_hh1 = (const float*)d_in[4];
  const float* b_ih1 = (const float*)d_in[5];
  const float* b_hh1 = (const float*)d_in[6];
  const float* W_ih2 = (const float*)d_in[7];
  const float* W_hh2 = (const float*)d_in[8];
  const float* b_ih2 = (const float*)d_in[9];
  const float* b_hh2 = (const float*)d_in[10];
  const float* W_out = (const float*)d_in[11];
  const float* b_out = (const float*)d_in[12];
  float* out = (float*)d_out;
  char* ws = (char*)d_ws;

  (void)in_sizes; (void)n_in; (void)out_size; (void)ws_size;

  hipFuncSetAttribute((const void*)gru_main,
                      hipFuncAttributeMaxDynamicSharedMemorySize, SMEM_BYTES);

  void* args[] = { (void*)&x,
                   (void*)&W_ih1, (void*)&W_hh1, (void*)&b_ih1, (void*)&b_hh1,
                   (void*)&W_ih2, (void*)&W_hh2, (void*)&b_ih2, (void*)&b_hh2,
                   (void*)&W_out, (void*)&b_out,
                   (void*)&h0in, (void*)&h1in,
                   (void*)&out, (void*)&ws };
  hipLaunchCooperativeKernel((const void*)gru_main, dim3(NBLK), dim3(256),
                             args, SMEM_BYTES, stream);
}